// Round 14
// baseline (54.183 us; speedup 1.0000x reference)
//
#include <hip/hip_runtime.h>
#include <hip/hip_bf16.h>
#include <hip/hip_fp8.h>

typedef float f32x16 __attribute__((ext_vector_type(16)));

constexpr int NROW = 8192;
constexpr int DCOL = 256;                  // row length in elements (= bytes in fp8)
constexpr int BM = 128;
constexpr int BKB = 128;                   // K-slab bytes (full 8-chunk swizzle period)
constexpr int NT = NROW / BM;              // 64 tile-rows
constexpr int NTILES = NT * (NT + 1) / 2;  // 2080 upper-tri tiles
constexpr int TPB = 4;                     // tiles per block
constexpr int NBLK = NTILES / TPB;         // 520 blocks  (520*4 == 2080, ~2.03/CU)
constexpr float MARGIN = 0.3f;

// async global->LDS, 16B per lane; LDS dest is wave-uniform base (HW adds lane*16)
__device__ inline void gload16(const unsigned char* g, unsigned char* l) {
    __builtin_amdgcn_global_load_lds(
        (const __attribute__((address_space(1))) void*)g,
        (__attribute__((address_space(3))) void*)l, 16, 0, 0);
}

// ---------------- normalize rows -> fp8 e4m3 ----------------
__global__ __launch_bounds__(256) void normalize_kernel(const float* __restrict__ hidden,
                                                        unsigned char* __restrict__ xn) {
    int wid = threadIdx.x >> 6, lane = threadIdx.x & 63;
    int row = (blockIdx.x << 2) + wid;
    const float4* src = reinterpret_cast<const float4*>(hidden + (size_t)row * DCOL);
    float4 v = src[lane];
    float ss = v.x * v.x + v.y * v.y + v.z * v.z + v.w * v.w;
    #pragma unroll
    for (int off = 32; off; off >>= 1) ss += __shfl_down(ss, off);
    ss = __shfl(ss, 0);
    float inv = 1.0f / fmaxf(sqrtf(ss), 1e-8f);
    __hip_fp8_e4m3 q0(v.x * inv), q1(v.y * inv), q2(v.z * inv), q3(v.w * inv);
    uchar4 o;
    o.x = *reinterpret_cast<unsigned char*>(&q0);
    o.y = *reinterpret_cast<unsigned char*>(&q1);
    o.z = *reinterpret_cast<unsigned char*>(&q2);
    o.w = *reinterpret_cast<unsigned char*>(&q3);
    reinterpret_cast<uchar4*>(xn + (size_t)row * DCOL)[lane] = o;
}

// ---------------- multi-tile persistent pipeline: 4 tiles/block, continuous dbuf ----------------
// 8 pipeline steps per block (4 tiles x 2 K-slabs), ONE exposed prologue; next tile's
// first slab is prefetched under current tile's last compute + epilogue (epilogue VALU
// hides load latency). Labels read direct from global (L1-resident); per-wave partials
// (no epilogue barrier).
__global__ __launch_bounds__(256) void pairloss_kernel(const unsigned char* __restrict__ xn,
                                                       const int* __restrict__ labels,
                                                       float* __restrict__ partials) {
    __shared__ unsigned char As[2][BM * BKB];   // 2 x 16KB
    __shared__ unsigned char Bs[2][BM * BKB];   // 2 x 16KB  (64KB total -> 2 blocks/CU)

    int tid = threadIdx.x;
    int wid = tid >> 6, lane = tid & 63;
    int wr = wid >> 1, wc = wid & 1;            // 2x2 waves, wave tile 64x64
    int lo = lane & 31, hi = lane >> 5;
    int srow = lane >> 3;                       // row within 8-row group
    int schunk = (lane & 7) ^ srow;             // pre-swizzled 16B source chunk (r&7 == srow)

    // unrank first tile of this block: linear id -> (bi, rem), bj = bi + rem
    int bi = 0, rem = (int)blockIdx.x * TPB;
    while (rem >= NT - bi) { rem -= NT - bi; ++bi; }
    int curBrow = bi * BM, curBcol = (bi + rem) * BM;

    auto stage = [&](int brow, int bcol, int s, int b) {   // 8 VMEM instr/thread
        const unsigned char* gA0 = xn + (size_t)brow * DCOL;
        const unsigned char* gB0 = xn + (size_t)bcol * DCOL;
        #pragma unroll
        for (int q = 0; q < 4; ++q) {
            int rg = (wid * 4 + q) * 8;                    // wave-uniform 8-row group
            int goff = (rg + srow) * DCOL + s * BKB + schunk * 16;
            gload16(gA0 + goff, &As[b][rg * BKB]);         // 8 rows x 128B, linear dest
            gload16(gB0 + goff, &Bs[b][rg * BKB]);
        }
    };

    stage(curBrow, curBcol, 0, 0);              // prologue: only exposed wait per block

    for (int k = 0; k < TPB; ++k) {
        // advance unrank state to tile k+1 (scalar, uniform)
        int nrem = rem + 1, nbi = bi;
        if (nrem >= NT - nbi) { nrem = 0; ++nbi; }
        int nxtBrow = nbi * BM, nxtBcol = (nbi + nrem) * BM;

        f32x16 acc[2][2] = {};                  // 2x2 tiles of 32x32 per wave

        auto compute = [&](int b) {
            #pragma unroll
            for (int kk = 0; kk < 8; ++kk) {    // K16 sub-steps of BKB=128
                long af[2], bfr[2];             // 8 fp8 = 2 VGPRs each
                #pragma unroll
                for (int m = 0; m < 2; ++m) {
                    int r = wr * 64 + m * 32 + lo;
                    af[m] = *reinterpret_cast<const long*>(
                        &As[b][r * BKB + ((kk ^ (r & 7)) << 4) + hi * 8]);
                }
                #pragma unroll
                for (int n = 0; n < 2; ++n) {
                    int r = wc * 64 + n * 32 + lo;
                    bfr[n] = *reinterpret_cast<const long*>(
                        &Bs[b][r * BKB + ((kk ^ (r & 7)) << 4) + hi * 8]);
                }
                __builtin_amdgcn_s_setprio(1);
                #pragma unroll
                for (int m = 0; m < 2; ++m)
                    #pragma unroll
                    for (int n = 0; n < 2; ++n)
                        acc[m][n] = __builtin_amdgcn_mfma_f32_32x32x16_fp8_fp8(af[m], bfr[n], acc[m][n], 0, 0, 0);
                __builtin_amdgcn_s_setprio(0);
            }
        };

        // slab 0: compute buf0, prefetch this tile's slab1 into buf1
        asm volatile("s_waitcnt vmcnt(0)" ::: "memory");
        __builtin_amdgcn_s_barrier();
        stage(curBrow, curBcol, 1, 1);
        compute(0);

        // slab 1: compute buf1, prefetch next tile's slab0 into buf0
        asm volatile("s_waitcnt vmcnt(0)" ::: "memory");
        __builtin_amdgcn_s_barrier();
        if (k + 1 < TPB) stage(nxtBrow, nxtBcol, 0, 0);
        compute(1);

        // epilogue: per-pair loss for this tile (overlaps the in-flight next-tile loads)
        // 32x32 C/D: col=lane&31, row=(reg&3)+8*(reg>>2)+4*(lane>>5)  (dtype-independent)
        {
            bool diag = (curBrow == curBcol);
            int lb0 = labels[curBcol + wc * 64 + lo];
            int lb1 = labels[curBcol + wc * 64 + 32 + lo];
            float local = 0.0f;
            #pragma unroll
            for (int m = 0; m < 2; ++m) {
                #pragma unroll
                for (int g = 0; g < 16; ++g) {
                    int crow = (g & 3) + 8 * (g >> 2) + 4 * hi;
                    int il = wr * 64 + m * 32 + crow;
                    int la = labels[curBrow + il];
                    {
                        float sim = acc[m][0][g];
                        float v = (la == lb0) ? (1.0f - sim) : fmaxf(sim - MARGIN, 0.0f);
                        if (diag) v = (il < wc * 64 + lo) ? v : 0.0f;
                        local += v;
                    }
                    {
                        float sim = acc[m][1][g];
                        float v = (la == lb1) ? (1.0f - sim) : fmaxf(sim - MARGIN, 0.0f);
                        if (diag) v = (il < wc * 64 + 32 + lo) ? v : 0.0f;
                        local += v;
                    }
                }
            }
            #pragma unroll
            for (int off = 32; off; off >>= 1) local += __shfl_down(local, off);
            if (lane == 0) partials[((int)blockIdx.x * TPB + k) * 4 + wid] = local;
        }

        bi = nbi; rem = nrem; curBrow = nxtBrow; curBcol = nxtBcol;
    }
}

// ---------------- reduce per-wave partials -> loss ----------------
__global__ __launch_bounds__(512) void finalize_kernel(const float* __restrict__ partials,
                                                       float* __restrict__ out) {
    __shared__ float wsum[8];
    int tid = threadIdx.x, wid = tid >> 6, lane = tid & 63;
    float s = 0.0f;
    for (int i = tid; i < NTILES * 4; i += 512) s += partials[i];
    #pragma unroll
    for (int off = 32; off; off >>= 1) s += __shfl_down(s, off);
    if (lane == 0) wsum[wid] = s;
    __syncthreads();
    if (tid == 0) {
        float total = 0.0f;
        #pragma unroll
        for (int w = 0; w < 8; ++w) total += wsum[w];
        out[0] = total * (1.0f / 33550336.0f);  // / (N*(N-1)/2)
    }
}

extern "C" void kernel_launch(void* const* d_in, const int* in_sizes, int n_in,
                              void* d_out, int out_size, void* d_ws, size_t ws_size,
                              hipStream_t stream) {
    const float* hidden = (const float*)d_in[0];
    const int* labels = (const int*)d_in[1];
    float* out = (float*)d_out;

    unsigned char* xn = (unsigned char*)d_ws;                          // 2 MB fp8
    float* partials = (float*)((char*)d_ws + (size_t)NROW * DCOL);     // 8320 floats

    normalize_kernel<<<NROW / 4, 256, 0, stream>>>(hidden, xn);
    pairloss_kernel<<<NBLK, 256, 0, stream>>>(xn, labels, partials);
    finalize_kernel<<<1, 512, 0, stream>>>(partials, out);
}

// Round 15
// 40.211 us; speedup vs baseline: 1.3475x; 1.3475x over previous
//
#include <hip/hip_runtime.h>
#include <hip/hip_bf16.h>
#include <hip/hip_fp8.h>

typedef float f32x16 __attribute__((ext_vector_type(16)));

constexpr int NROW = 8192;
constexpr int DCOL = 256;                  // row length in elements (= bytes in fp8)
constexpr int BM = 128;
constexpr int BKB = 128;                   // K-slab bytes (full 8-chunk swizzle period)
constexpr int NT = NROW / BM;              // 64
constexpr int NTILES = NT * (NT + 1) / 2;  // 2080 (divisible by 8)
constexpr float MARGIN = 0.3f;

// async global->LDS, 16B per lane; LDS dest is wave-uniform base (HW adds lane*16)
__device__ inline void gload16(const unsigned char* g, unsigned char* l) {
    __builtin_amdgcn_global_load_lds(
        (const __attribute__((address_space(1))) void*)g,
        (__attribute__((address_space(3))) void*)l, 16, 0, 0);
}

// ---------------- normalize rows -> fp8 e4m3 ----------------
__global__ __launch_bounds__(256) void normalize_kernel(const float* __restrict__ hidden,
                                                        unsigned char* __restrict__ xn) {
    int wid = threadIdx.x >> 6, lane = threadIdx.x & 63;
    int row = (blockIdx.x << 2) + wid;
    const float4* src = reinterpret_cast<const float4*>(hidden + (size_t)row * DCOL);
    float4 v = src[lane];
    float ss = v.x * v.x + v.y * v.y + v.z * v.z + v.w * v.w;
    #pragma unroll
    for (int off = 32; off; off >>= 1) ss += __shfl_down(ss, off);
    ss = __shfl(ss, 0);
    float inv = 1.0f / fmaxf(sqrtf(ss), 1e-8f);
    __hip_fp8_e4m3 q0(v.x * inv), q1(v.y * inv), q2(v.z * inv), q3(v.w * inv);
    uchar4 o;
    o.x = *reinterpret_cast<unsigned char*>(&q0);
    o.y = *reinterpret_cast<unsigned char*>(&q1);
    o.z = *reinterpret_cast<unsigned char*>(&q2);
    o.w = *reinterpret_cast<unsigned char*>(&q3);
    reinterpret_cast<uchar4*>(xn + (size_t)row * DCOL)[lane] = o;
}

// ---------------- 128x128-tile, 4-wave fp8 MFMA Gram + fused pair loss --------
// r13 base + both K-slabs pre-staged in prologue; first wait counted vmcnt(8)
// (slab1's 8 loads stay in flight under compute(0)). Exactly 2 waits + 2 barriers
// per block, no LDS reuse -> no WAR barriers, no mid-compute VMEM issue.
__global__ __launch_bounds__(256) void pairloss_kernel(const unsigned char* __restrict__ xn,
                                                       const int* __restrict__ labels,
                                                       float* __restrict__ partials) {
    __shared__ unsigned char As[2][BM * BKB];   // 2 x 16KB (slab0, slab1)
    __shared__ unsigned char Bs[2][BM * BKB];   // 2 x 16KB
    __shared__ int lblA[BM], lblB[BM];
    __shared__ float wsum[4];

    // XCD-aware bijective swizzle
    int bid = (int)(blockIdx.x & 7) * (NTILES / 8) + (int)(blockIdx.x >> 3);
    int bi = 0, rem = bid;
    while (rem >= NT - bi) { rem -= NT - bi; ++bi; }
    int bj = bi + rem;

    int tid = threadIdx.x;
    int wid = tid >> 6, lane = tid & 63;
    int wr = wid >> 1, wc = wid & 1;            // 2x2 waves, wave tile 64x64
    int brow = bi * BM, bcol = bj * BM;

    if (tid < BM) lblA[tid] = labels[brow + tid];
    else          lblB[tid - BM] = labels[bcol + tid - BM];

    f32x16 acc[2][2] = {};                      // 2x2 tiles of 32x32 per wave

    int srow = lane >> 3;                       // row within 8-row group
    int schunk = (lane & 7) ^ srow;             // pre-swizzled 16B source chunk (r&7 == srow)
    const unsigned char* gA0 = xn + (size_t)brow * DCOL;
    const unsigned char* gB0 = xn + (size_t)bcol * DCOL;
    int lo = lane & 31, hi = lane >> 5;

    auto stage = [&](int s) {                   // 8 VMEM instr/thread per slab
        #pragma unroll
        for (int q = 0; q < 4; ++q) {
            int rg = (wid * 4 + q) * 8;         // wave-uniform 8-row group
            int goff = (rg + srow) * DCOL + s * BKB + schunk * 16;
            gload16(gA0 + goff, &As[s][rg * BKB]);   // 8 rows x 128B, linear dest
            gload16(gB0 + goff, &Bs[s][rg * BKB]);
        }
    };
    auto compute = [&](int b) {
        #pragma unroll
        for (int kk = 0; kk < 8; ++kk) {        // K16 sub-steps of BKB=128
            long af[2], bfr[2];                 // 8 fp8 = 2 VGPRs each
            #pragma unroll
            for (int m = 0; m < 2; ++m) {
                int r = wr * 64 + m * 32 + lo;  // r&7 == lane&7
                af[m] = *reinterpret_cast<const long*>(
                    &As[b][r * BKB + ((kk ^ (r & 7)) << 4) + hi * 8]);
            }
            #pragma unroll
            for (int n = 0; n < 2; ++n) {
                int r = wc * 64 + n * 32 + lo;
                bfr[n] = *reinterpret_cast<const long*>(
                    &Bs[b][r * BKB + ((kk ^ (r & 7)) << 4) + hi * 8]);
            }
            __builtin_amdgcn_s_setprio(1);
            #pragma unroll
            for (int m = 0; m < 2; ++m)
                #pragma unroll
                for (int n = 0; n < 2; ++n)
                    acc[m][n] = __builtin_amdgcn_mfma_f32_32x32x16_fp8_fp8(af[m], bfr[n], acc[m][n], 0, 0, 0);
            __builtin_amdgcn_s_setprio(0);
        }
    };

    stage(0);                                   // 8 loads: slab0
    stage(1);                                   // 8 loads: slab1 (stays in flight)
    asm volatile("s_waitcnt vmcnt(8)" ::: "memory");   // slab0's 8 oldest done
    __builtin_amdgcn_s_barrier();               // all waves' slab0 landed (each waited its own)
    compute(0);
    asm volatile("s_waitcnt vmcnt(0)" ::: "memory");   // slab1: issued ~2000cyc ago, covered
    __builtin_amdgcn_s_barrier();
    compute(1);

    // epilogue: per-pair loss, strict upper triangle
    // 32x32 C/D: col = lane&31, row = (reg&3) + 8*(reg>>2) + 4*(lane>>5)  (dtype-independent)
    float local = 0.0f;
    #pragma unroll
    for (int m = 0; m < 2; ++m) {
        #pragma unroll
        for (int n = 0; n < 2; ++n) {
            #pragma unroll
            for (int g = 0; g < 16; ++g) {
                int crow = (g & 3) + 8 * (g >> 2) + 4 * hi;
                int il = wr * 64 + m * 32 + crow;
                int jl = wc * 64 + n * 32 + lo;
                int gi = brow + il, gj = bcol + jl;
                float sim = acc[m][n][g];
                float v = (lblA[il] == lblB[jl]) ? (1.0f - sim) : fmaxf(sim - MARGIN, 0.0f);
                local += (gi < gj) ? v : 0.0f;
            }
        }
    }
    #pragma unroll
    for (int off = 32; off; off >>= 1) local += __shfl_down(local, off);
    if (lane == 0) wsum[wid] = local;
    __syncthreads();
    if (tid == 0) partials[bid] = wsum[0] + wsum[1] + wsum[2] + wsum[3];
}

// ---------------- reduce partials -> loss ----------------
__global__ __launch_bounds__(512) void finalize_kernel(const float* __restrict__ partials,
                                                       float* __restrict__ out) {
    __shared__ float wsum[8];
    int tid = threadIdx.x, wid = tid >> 6, lane = tid & 63;
    float s = 0.0f;
    for (int i = tid; i < NTILES; i += 512) s += partials[i];
    #pragma unroll
    for (int off = 32; off; off >>= 1) s += __shfl_down(s, off);
    if (lane == 0) wsum[wid] = s;
    __syncthreads();
    if (tid == 0) {
        float total = 0.0f;
        #pragma unroll
        for (int w = 0; w < 8; ++w) total += wsum[w];
        out[0] = total * (1.0f / 33550336.0f);  // / (N*(N-1)/2)
    }
}

extern "C" void kernel_launch(void* const* d_in, const int* in_sizes, int n_in,
                              void* d_out, int out_size, void* d_ws, size_t ws_size,
                              hipStream_t stream) {
    const float* hidden = (const float*)d_in[0];
    const int* labels = (const int*)d_in[1];
    float* out = (float*)d_out;

    unsigned char* xn = (unsigned char*)d_ws;                          // 2 MB fp8
    float* partials = (float*)((char*)d_ws + (size_t)NROW * DCOL);     // 2080 floats

    normalize_kernel<<<NROW / 4, 256, 0, stream>>>(hidden, xn);
    pairloss_kernel<<<NTILES, 256, 0, stream>>>(xn, labels, partials);
    finalize_kernel<<<1, 512, 0, stream>>>(partials, out);
}

// Round 16
// 34.174 us; speedup vs baseline: 1.5855x; 1.1767x over previous
//
#include <hip/hip_runtime.h>
#include <hip/hip_bf16.h>
#include <hip/hip_fp8.h>

typedef float f32x16 __attribute__((ext_vector_type(16)));

constexpr int NROW = 8192;
constexpr int DCOL = 256;                  // row length in elements (= bytes in fp8)
constexpr int BM = 128;
constexpr int BKB = 128;                   // K-slab bytes (full 8-chunk swizzle period)
constexpr int NT = NROW / BM;              // 64
constexpr int NTILES = NT * (NT + 1) / 2;  // 2080 (divisible by 8)
constexpr float MARGIN = 0.3f;

// async global->LDS, 16B per lane; LDS dest is wave-uniform base (HW adds lane*16)
__device__ inline void gload16(const unsigned char* g, unsigned char* l) {
    __builtin_amdgcn_global_load_lds(
        (const __attribute__((address_space(1))) void*)g,
        (__attribute__((address_space(3))) void*)l, 16, 0, 0);
}

// ---------------- normalize rows -> fp8 e4m3 ----------------
__global__ __launch_bounds__(256) void normalize_kernel(const float* __restrict__ hidden,
                                                        unsigned char* __restrict__ xn) {
    int wid = threadIdx.x >> 6, lane = threadIdx.x & 63;
    int row = (blockIdx.x << 2) + wid;
    const float4* src = reinterpret_cast<const float4*>(hidden + (size_t)row * DCOL);
    float4 v = src[lane];
    float ss = v.x * v.x + v.y * v.y + v.z * v.z + v.w * v.w;
    #pragma unroll
    for (int off = 32; off; off >>= 1) ss += __shfl_down(ss, off);
    ss = __shfl(ss, 0);
    float inv = 1.0f / fmaxf(sqrtf(ss), 1e-8f);
    __hip_fp8_e4m3 q0(v.x * inv), q1(v.y * inv), q2(v.z * inv), q3(v.w * inv);
    uchar4 o;
    o.x = *reinterpret_cast<unsigned char*>(&q0);
    o.y = *reinterpret_cast<unsigned char*>(&q1);
    o.z = *reinterpret_cast<unsigned char*>(&q2);
    o.w = *reinterpret_cast<unsigned char*>(&q3);
    reinterpret_cast<uchar4*>(xn + (size_t)row * DCOL)[lane] = o;
}

// ---------------- 128x128-tile, 4-wave fp8 MFMA Gram + fused pair loss --------
// Single-slab LDS (34KB) -> 4 blocks/CU -> 4 waves/SIMD: the latency-chain model from
// the r8 probe (13.9us = per-wave chain x rounds x NO wave overlap at 2/SIMD) says
// waves/SIMD is the divisor for the stall-dominated portion. Serial 2-drain structure;
// drains covered by 3 co-resident blocks. VGPR<=128 keeps 16 waves/CU legal.
__global__ __launch_bounds__(256) void pairloss_kernel(const unsigned char* __restrict__ xn,
                                                       const int* __restrict__ labels,
                                                       float* __restrict__ partials) {
    __shared__ unsigned char As[BM * BKB];      // 16KB, one K-slab
    __shared__ unsigned char Bs[BM * BKB];      // 16KB
    __shared__ int lblA[BM], lblB[BM];
    __shared__ float wsum[4];

    // XCD-aware bijective swizzle
    int bid = (int)(blockIdx.x & 7) * (NTILES / 8) + (int)(blockIdx.x >> 3);
    int bi = 0, rem = bid;
    while (rem >= NT - bi) { rem -= NT - bi; ++bi; }
    int bj = bi + rem;

    int tid = threadIdx.x;
    int wid = tid >> 6, lane = tid & 63;
    int wr = wid >> 1, wc = wid & 1;            // 2x2 waves, wave tile 64x64
    int brow = bi * BM, bcol = bj * BM;

    if (tid < BM) lblA[tid] = labels[brow + tid];
    else          lblB[tid - BM] = labels[bcol + tid - BM];

    f32x16 acc[2][2] = {};                      // 2x2 tiles of 32x32 per wave

    int srow = lane >> 3;                       // row within 8-row group
    int schunk = (lane & 7) ^ srow;             // pre-swizzled 16B source chunk (r&7 == srow)
    const unsigned char* gA0 = xn + (size_t)brow * DCOL;
    const unsigned char* gB0 = xn + (size_t)bcol * DCOL;
    int lo = lane & 31, hi = lane >> 5;

    auto stage = [&](int s) {                   // 8 VMEM instr/thread per slab
        #pragma unroll
        for (int q = 0; q < 4; ++q) {
            int rg = (wid * 4 + q) * 8;         // wave-uniform 8-row group
            int goff = (rg + srow) * DCOL + s * BKB + schunk * 16;
            gload16(gA0 + goff, &As[rg * BKB]); // 8 rows x 128B, linear dest
            gload16(gB0 + goff, &Bs[rg * BKB]);
        }
    };
    auto compute = [&]() {
        #pragma unroll
        for (int kk = 0; kk < 8; ++kk) {        // K16 sub-steps of BKB=128
            long af[2], bfr[2];                 // 8 fp8 = 2 VGPRs each
            #pragma unroll
            for (int m = 0; m < 2; ++m) {
                int r = wr * 64 + m * 32 + lo;  // r&7 == lane&7
                af[m] = *reinterpret_cast<const long*>(
                    &As[r * BKB + ((kk ^ (r & 7)) << 4) + hi * 8]);
            }
            #pragma unroll
            for (int n = 0; n < 2; ++n) {
                int r = wc * 64 + n * 32 + lo;
                bfr[n] = *reinterpret_cast<const long*>(
                    &Bs[r * BKB + ((kk ^ (r & 7)) << 4) + hi * 8]);
            }
            __builtin_amdgcn_s_setprio(1);
            #pragma unroll
            for (int m = 0; m < 2; ++m)
                #pragma unroll
                for (int n = 0; n < 2; ++n)
                    acc[m][n] = __builtin_amdgcn_mfma_f32_32x32x16_fp8_fp8(af[m], bfr[n], acc[m][n], 0, 0, 0);
            __builtin_amdgcn_s_setprio(0);
        }
    };

    stage(0);
    asm volatile("s_waitcnt vmcnt(0)" ::: "memory");
    __builtin_amdgcn_s_barrier();               // slab0 landed for all waves
    compute();
    __builtin_amdgcn_s_barrier();               // all readers done before overwrite
    stage(1);
    asm volatile("s_waitcnt vmcnt(0)" ::: "memory");
    __builtin_amdgcn_s_barrier();               // slab1 landed
    compute();

    // epilogue: per-pair loss, strict upper triangle
    // 32x32 C/D: col = lane&31, row = (reg&3) + 8*(reg>>2) + 4*(lane>>5)  (dtype-independent)
    float local = 0.0f;
    #pragma unroll
    for (int m = 0; m < 2; ++m) {
        #pragma unroll
        for (int n = 0; n < 2; ++n) {
            #pragma unroll
            for (int g = 0; g < 16; ++g) {
                int crow = (g & 3) + 8 * (g >> 2) + 4 * hi;
                int il = wr * 64 + m * 32 + crow;
                int jl = wc * 64 + n * 32 + lo;
                int gi = brow + il, gj = bcol + jl;
                float sim = acc[m][n][g];
                float v = (lblA[il] == lblB[jl]) ? (1.0f - sim) : fmaxf(sim - MARGIN, 0.0f);
                local += (gi < gj) ? v : 0.0f;
            }
        }
    }
    #pragma unroll
    for (int off = 32; off; off >>= 1) local += __shfl_down(local, off);
    if (lane == 0) wsum[wid] = local;
    __syncthreads();
    if (tid == 0) partials[bid] = wsum[0] + wsum[1] + wsum[2] + wsum[3];
}

// ---------------- reduce partials -> loss ----------------
__global__ __launch_bounds__(512) void finalize_kernel(const float* __restrict__ partials,
                                                       float* __restrict__ out) {
    __shared__ float wsum[8];
    int tid = threadIdx.x, wid = tid >> 6, lane = tid & 63;
    float s = 0.0f;
    for (int i = tid; i < NTILES; i += 512) s += partials[i];
    #pragma unroll
    for (int off = 32; off; off >>= 1) s += __shfl_down(s, off);
    if (lane == 0) wsum[wid] = s;
    __syncthreads();
    if (tid == 0) {
        float total = 0.0f;
        #pragma unroll
        for (int w = 0; w < 8; ++w) total += wsum[w];
        out[0] = total * (1.0f / 33550336.0f);  // / (N*(N-1)/2)
    }
}

extern "C" void kernel_launch(void* const* d_in, const int* in_sizes, int n_in,
                              void* d_out, int out_size, void* d_ws, size_t ws_size,
                              hipStream_t stream) {
    const float* hidden = (const float*)d_in[0];
    const int* labels = (const int*)d_in[1];
    float* out = (float*)d_out;

    unsigned char* xn = (unsigned char*)d_ws;                          // 2 MB fp8
    float* partials = (float*)((char*)d_ws + (size_t)NROW * DCOL);     // 2080 floats

    normalize_kernel<<<NROW / 4, 256, 0, stream>>>(hidden, xn);
    pairloss_kernel<<<NTILES, 256, 0, stream>>>(xn, labels, partials);
    finalize_kernel<<<1, 512, 0, stream>>>(partials, out);
}